// Round 9
// baseline (470.647 us; speedup 1.0000x reference)
//
#include <hip/hip_runtime.h>
#include <stdint.h>

#define NROWS 500000
#define NROWS4 125000
#define NCLS 100
#define NBINS 15
#define NSUB 64          // sub-bucket = 4096 ULP; ~70 elems/sub near mode -> rank err << tolerance
#define B1 14
#define CH1 8929         // ceil(125000/14) float4s per hist1 block
#define B2 28
#define CH2 4465         // ceil(125000/28) float4s per scan2 block
#define HSZ (NBINS * NSUB)   // 960
#define FPS 16777216.0f      // 2^24 fixed-point scale
#define FPI (1.0 / 16777216.0)

__device__ __forceinline__ int rank_target(int b) {
    if (b == 0) return 0;
    const float step = 500000.0f / 15.0f;   // float32-rounded, mimics jnp.linspace
    return (int)floorf((float)b * step);
}

// Pass 1: row softmax of logits [N][C], write transposed probsT [C][N].
// float4 loads, 4-adjacent-lane shfl reduction (exact old summation order ->
// bit-identical probs), 2 syncthreads.  Emits labConf[n] = prob of labeled
// class so k_label never gathers probsT.  (Rounds 5-6: issue/latency tuning
// null -> bound by its ~400MB memory traffic.)
__global__ __launch_bounds__(256) void k_softmax_t(const float4* __restrict__ logits4,
                                                   const int* __restrict__ labels,
                                                   float* __restrict__ probsT,
                                                   float* __restrict__ labConf) {
    __shared__ float tile[64][101];
    __shared__ float inv[64];
    const int row0 = blockIdx.x * 64;
    const int rows = min(64, NROWS - row0);
    const int t = threadIdx.x;
    const float4* lg4 = logits4 + (size_t)row0 * 25;
    const int total4 = rows * 25;
    for (int k = t; k < total4; k += 256) {
        float4 v = lg4[k];
        int r = k / 25, c4 = (k - r * 25) * 4;
        tile[r][c4 + 0] = v.x; tile[r][c4 + 1] = v.y;
        tile[r][c4 + 2] = v.z; tile[r][c4 + 3] = v.w;
    }
    __syncthreads();
    const int r = t >> 2, q = t & 3;   // 4 adjacent lanes per row
    if (r < rows) {
        float m = -1e30f;
        #pragma unroll
        for (int c = 0; c < 25; ++c) m = fmaxf(m, tile[r][q * 25 + c]);
        const int lb = t & ~3;
        float m0 = __shfl(m, lb + 0, 64), m1 = __shfl(m, lb + 1, 64);
        float m2 = __shfl(m, lb + 2, 64), m3 = __shfl(m, lb + 3, 64);
        m = fmaxf(fmaxf(m0, m1), fmaxf(m2, m3));
        float s = 0.f;
        #pragma unroll
        for (int c = 0; c < 25; ++c) {
            float e = __expf(tile[r][q * 25 + c] - m);
            tile[r][q * 25 + c] = e;
            s += e;
        }
        float s0 = __shfl(s, lb + 0, 64), s1 = __shfl(s, lb + 1, 64);
        float s2 = __shfl(s, lb + 2, 64), s3 = __shfl(s, lb + 3, 64);
        if (q == 0) inv[r] = 1.0f / (((s0 + s1) + s2) + s3);
    }
    __syncthreads();
    if (t < rows) {
        const int lab = labels[row0 + t];
        labConf[row0 + t] = tile[t][lab] * inv[t];
    }
    const int shift = (rows == 64) ? 4 : 3;
    const int gq = 1 << shift;
    const int ng = NCLS << shift;
    for (int k = t; k < ng; k += 256) {
        int c = k >> shift, g = k & (gq - 1);
        int rr = g << 2;
        float4 o;
        o.x = tile[rr + 0][c] * inv[rr + 0];
        o.y = tile[rr + 1][c] * inv[rr + 1];
        o.z = tile[rr + 2][c] * inv[rr + 2];
        o.w = tile[rr + 3][c] * inv[rr + 3];
        *(float4*)(probsT + (size_t)c * NROWS + row0 + rr) = o;
    }
}

// Pass 2: per-class L1 histogram (top 12 used float bits), 2 bank-rotated LDS
// copies.  Round-9: flush via zero-filtered GLOBAL u32 atomics into histG
// [NCLS][4096] (1.6MB, cache-resident) instead of 22.9MB of private copies --
// deletes the write AND sel1's 14x re-read (validated pattern: segG atomics).
__global__ __launch_bounds__(256) void k_hist1(const float4* __restrict__ probsT4,
                                               unsigned* __restrict__ histG) {
    __shared__ int h[2][4096];   // 32 KB
    const int c = blockIdx.y, t = threadIdx.x;
    int4* hz = (int4*)&h[0][0];
    for (int i = t; i < 2048; i += 256) hz[i] = make_int4(0, 0, 0, 0);
    __syncthreads();
    const int copy = t & 1;
    const int rot = copy << 4;
    const size_t base = (size_t)c * NROWS4;
    const int start = blockIdx.x * CH1;
    const int end = min(NROWS4, start + CH1);
    auto proc = [&](float4 v) {
        atomicAdd(&h[copy][((__float_as_uint(v.x) >> 18) + rot) & 4095], 1);
        atomicAdd(&h[copy][((__float_as_uint(v.y) >> 18) + rot) & 4095], 1);
        atomicAdd(&h[copy][((__float_as_uint(v.z) >> 18) + rot) & 4095], 1);
        atomicAdd(&h[copy][((__float_as_uint(v.w) >> 18) + rot) & 4095], 1);
    };
    int i = start + t;
    for (; i + 768 < end; i += 1024) {
        float4 w0 = probsT4[base + i];
        float4 w1 = probsT4[base + i + 256];
        float4 w2 = probsT4[base + i + 512];
        float4 w3 = probsT4[base + i + 768];
        proc(w0); proc(w1); proc(w2); proc(w3);
    }
    for (; i < end; i += 256) proc(probsT4[base + i]);
    __syncthreads();
    unsigned* out = histG + (size_t)c * 4096;
    for (int i2 = t; i2 < 4096; i2 += 256) {
        int v = h[0][i2] + h[1][(i2 + 16) & 4095];
        if (v) atomicAdd(&out[i2], (unsigned)v);
    }
}

// Select L1 bucket per rank target from the single merged histG; parallel
// prefix (shfl), dedupe via owner[] (owner = LAST slot of a duplicate-target
// group, matching scan2's upper_bound table semantics)
__global__ __launch_bounds__(256) void k_sel1(const unsigned* __restrict__ histG,
                                              int* __restrict__ tgt,
                                              int* __restrict__ below,
                                              int* __restrict__ owner) {
    __shared__ int wsum[4];
    __shared__ int stgt[NBINS];
    __shared__ int sbelow[NBINS];
    const int c = blockIdx.x, t = threadIdx.x;
    int loc[16];
    {
        const int4* p = (const int4*)(histG + (size_t)c * 4096) + t * 4;
        #pragma unroll
        for (int j = 0; j < 4; ++j) {
            int4 v = p[j];
            loc[j * 4 + 0] = v.x; loc[j * 4 + 1] = v.y;
            loc[j * 4 + 2] = v.z; loc[j * 4 + 3] = v.w;
        }
    }
    int s = 0;
    #pragma unroll
    for (int i = 0; i < 16; ++i) s += loc[i];
    // block-wide exclusive prefix of per-thread totals
    const int lane = t & 63, w = t >> 6;
    int incl = s;
    #pragma unroll
    for (int d = 1; d < 64; d <<= 1) {
        int n = __shfl_up(incl, d, 64);
        if (lane >= d) incl += n;
    }
    if (lane == 63) wsum[w] = incl;
    __syncthreads();
    int woff = 0;
    #pragma unroll
    for (int j = 0; j < 4; ++j) if (j < w) woff += wsum[j];
    const int cum0 = woff + incl - s;
    for (int b = 0; b < NBINS; ++b) {
        const int f = rank_target(b);
        int cc = cum0;
        #pragma unroll
        for (int i = 0; i < 16; ++i) {
            if (f >= cc && f < cc + loc[i]) { stgt[b] = t * 16 + i; sbelow[b] = cc; }
            cc += loc[i];
        }
    }
    __syncthreads();
    if (t == 0) {
        int ow = NBINS - 1;
        for (int b = NBINS - 1; b >= 0; --b) {
            if (b == NBINS - 1 || stgt[b] != stgt[b + 1]) ow = b;   // last-of-group
            owner[c * NBINS + b] = ow;
            tgt[c * NBINS + b] = stgt[b];
            below[c * NBINS + b] = sbelow[b];
        }
    }
}

// Pass 3: segment formulation, INT-ONLY LDS atomics, packed u64 segment slots.
// Round-9: sub-hist flush via zero-filtered GLOBAL atomics into hnG/hTG/hQG
// [NCLS][960] (1.9MB, cache-resident) instead of 32MB of private copies.
// T/Q sums become exact integers end-to-end (strictly better numerics).
__global__ __launch_bounds__(256) void k_scan2(const float4* __restrict__ probsT4,
                                               const int* __restrict__ tgt,
                                               unsigned* __restrict__ hnG,
                                               unsigned long long* __restrict__ hTG,
                                               unsigned long long* __restrict__ hQG,
                                               unsigned long long* __restrict__ segG) {
    __shared__ int stg[16];
    __shared__ unsigned char tbl[4096];
    __shared__ unsigned long long seg[16][128];  // 16 KB: hi32 = T, lo32 = Q
    __shared__ unsigned hn[HSZ];                 // 3.84 KB
    __shared__ unsigned long long hT[HSZ];       // 7.68 KB
    __shared__ unsigned long long hQ[HSZ];       // 7.68 KB
    const int c = blockIdx.y, t = threadIdx.x;
    if (t < 16) stg[t] = (t < NBINS) ? tgt[c * NBINS + t] : 0x7FFFFFFF;
    for (int i = t; i < 4096; i += 256) ((unsigned*)&seg[0][0])[i] = 0u;
    for (int i = t; i < HSZ; i += 256) { hn[i] = 0u; hT[i] = 0ull; hQ[i] = 0ull; }
    __syncthreads();                      // stg ready
    // build bucket->segment table: tbl[k] = #{b : stg[b] <= k} (upper_bound)
    {
        const int k0 = t * 16;
        int j = 0;
        j += (stg[j + 7] <= k0) ? 8 : 0;
        j += (stg[j + 3] <= k0) ? 4 : 0;
        j += (stg[j + 1] <= k0) ? 2 : 0;
        j += (stg[j] <= k0) ? 1 : 0;
        for (int k = k0; k < k0 + 16; ++k) {
            while (j < NBINS && stg[j] <= k) ++j;
            tbl[k] = (unsigned char)j;
        }
    }
    __syncthreads();                      // j-values filled
    if (t < NBINS) tbl[stg[t]] |= 0x80;   // flag target buckets (dupes idempotent)
    __syncthreads();
    const size_t base = (size_t)c * NROWS4;
    const int start = blockIdx.x * CH2;
    const int end = min(NROWS4, start + CH2);
    const int col = t & 127;
    auto emit = [&](float v, unsigned bx, unsigned b8) {
        const int j = (int)(b8 & 15u);
        const unsigned vT = (unsigned)fmaf(v, FPS, 0.5f);
        const unsigned vQ = (unsigned)fmaf(v * v, FPS, 0.5f);
        atomicAdd(&seg[j][col], ((unsigned long long)vT << 32) | (unsigned long long)vQ);
        if (b8 & 0x80u) {                 // inside a target bucket: sub-histogram
            int sub = (j - 1) * NSUB + (int)((bx >> 12) & (NSUB - 1));
            atomicAdd(&hn[sub], 1u);
            atomicAdd(&hT[sub], (unsigned long long)vT);   // ds_add_u64
            atomicAdd(&hQ[sub], (unsigned long long)vQ);
        }
    };
    int i = start + t;
    for (; i + 768 < end; i += 1024) {
        float4 w0 = probsT4[base + i];
        float4 w1 = probsT4[base + i + 256];
        float4 w2 = probsT4[base + i + 512];
        float4 w3 = probsT4[base + i + 768];
        float va[16] = {w0.x, w0.y, w0.z, w0.w, w1.x, w1.y, w1.z, w1.w,
                        w2.x, w2.y, w2.z, w2.w, w3.x, w3.y, w3.z, w3.w};
        unsigned bxa[16], b8a[16];
        #pragma unroll
        for (int e = 0; e < 16; ++e) bxa[e] = __float_as_uint(va[e]);
        #pragma unroll
        for (int e = 0; e < 16; ++e) b8a[e] = (unsigned)tbl[bxa[e] >> 18];  // gather burst
        #pragma unroll
        for (int e = 0; e < 16; ++e) emit(va[e], bxa[e], b8a[e]);
    }
    for (; i < end; i += 256) {
        float4 v = probsT4[base + i];
        float va[4] = {v.x, v.y, v.z, v.w};
        unsigned bxa[4], b8a[4];
        #pragma unroll
        for (int e = 0; e < 4; ++e) bxa[e] = __float_as_uint(va[e]);
        #pragma unroll
        for (int e = 0; e < 4; ++e) b8a[e] = (unsigned)tbl[bxa[e] >> 18];
        #pragma unroll
        for (int e = 0; e < 4; ++e) emit(va[e], bxa[e], b8a[e]);
    }
    __syncthreads();
    // flush sub-hists: zero-filtered global atomics (hn==0 => hT==hQ==0)
    {
        const size_t gb = (size_t)c * HSZ;
        for (int i2 = t; i2 < HSZ; i2 += 256) {
            unsigned n = hn[i2];
            if (n) {
                atomicAdd(&hnG[gb + i2], n);
                atomicAdd(&hTG[gb + i2], hT[i2]);
                atomicAdd(&hQG[gb + i2], hQ[i2]);
            }
        }
    }
    // reduce seg slots (16 threads per segment, 8 slots each) -> global u64 atomics
    {
        const int j = t >> 4, p = t & 15;
        unsigned long long sT = 0ull, sQ = 0ull;
        #pragma unroll
        for (int i2 = 0; i2 < 8; ++i2) {
            unsigned long long wv = seg[j][p * 8 + i2];
            sT += (wv >> 32);
            sQ += (wv & 0xFFFFFFFFull);
        }
        #pragma unroll
        for (int o = 8; o; o >>= 1) {
            sT += __shfl_xor(sT, o, 64);
            sQ += __shfl_xor(sQ, o, 64);
        }
        if (p == 0) {
            atomicAdd(&segG[c * 32 + 2 * j], sT);
            atomicAdd(&segG[c * 32 + 2 * j + 1], sQ);
        }
    }
}

// Select sub-bucket (single wave, shfl prefix over 64 subs) from the merged
// global sub-hist tables; cumulative {N,T,Q} at the boundary, exact integer
// arithmetic: cumT[b] = (sum_{j<=b} segG_T[j] + sub-prefix) * 2^-24
__global__ __launch_bounds__(64) void k_sel2(const unsigned* __restrict__ hnG,
                                             const unsigned long long* __restrict__ hTG,
                                             const unsigned long long* __restrict__ hQG,
                                             const int* __restrict__ tgt,
                                             const int* __restrict__ below,
                                             const int* __restrict__ owner,
                                             const unsigned long long* __restrict__ segG,
                                             float* __restrict__ bounds,
                                             int* __restrict__ cumN,
                                             double* __restrict__ cumT,
                                             double* __restrict__ cumQ) {
    const int b = blockIdx.x, c = blockIdx.y, t = threadIdx.x;   // t < 64
    const int ow = owner[c * NBINS + b];
    const size_t gi = (size_t)c * HSZ + ow * NSUB + t;
    int nj = (int)hnG[gi];
    unsigned long long Tj = hTG[gi];
    unsigned long long Qj = hQG[gi];
    const int own = nj;
    #pragma unroll
    for (int d = 1; d < 64; d <<= 1) {
        int nn = __shfl_up(nj, d, 64);
        unsigned long long TT = __shfl_up(Tj, d, 64);
        unsigned long long QQ = __shfl_up(Qj, d, 64);
        if (t >= d) { nj += nn; Tj += TT; Qj += QQ; }
    }
    const int bel = below[c * NBINS + b];
    const int lr = rank_target(b) - bel;
    if (lr >= nj - own && lr < nj) {
        unsigned bits = ((unsigned)tgt[c * NBINS + b] << 18) | ((unsigned)t << 12) | 0xFFFu;
        bounds[c * NBINS + b] = __uint_as_float(bits);
        cumN[c * NBINS + b] = bel + nj;
        unsigned long long A = 0ull, Qd = 0ull;
        for (int jj = 0; jj <= b; ++jj) {
            A  += segG[c * 32 + 2 * jj];
            Qd += segG[c * 32 + 2 * jj + 1];
        }
        cumT[c * NBINS + b] = (double)(A + Tj) * FPI;    // exact: < 2^53
        cumQ[c * NBINS + b] = (double)(Qd + Qj) * FPI;
    }
}

// Pass 4: label correction from the compact labConf array (coalesced), LDS-staged
// bounds + u64 fixed-point LDS accumulator (int atomics, no FP-CAS), one
// filtered global u64-atomic flush per block
__global__ __launch_bounds__(256) void k_label(const float* __restrict__ labConf,
                                               const int* __restrict__ labels,
                                               const float* __restrict__ bounds,
                                               unsigned long long* __restrict__ accLab) {
    __shared__ float sbd[NCLS * NBINS];                  // 6 KB
    __shared__ unsigned long long sacc[NCLS * NBINS * 2];// 24 KB
    const int t = threadIdx.x;
    for (int i = t; i < NCLS * NBINS; i += 256) sbd[i] = bounds[i];
    for (int i = t; i < NCLS * NBINS * 2; i += 256) sacc[i] = 0ull;
    __syncthreads();
    for (int n = blockIdx.x * 256 + t; n < NROWS; n += gridDim.x * 256) {
        const int c = labels[n];
        const float conf = labConf[n];
        const float* bd = sbd + c * NBINS;
        if (conf > bd[0]) {
            int idx = 0;
            #pragma unroll
            for (int b = 1; b < NBINS; ++b) idx += (conf > bd[b]) ? 1 : 0;
            atomicAdd(&sacc[(c * NBINS + idx) * 2 + 0], 1ull);
            atomicAdd(&sacc[(c * NBINS + idx) * 2 + 1],
                      (unsigned long long)(unsigned)fmaf(conf, FPS, 0.5f));
        }
    }
    __syncthreads();
    for (int i = t; i < NCLS * NBINS * 2; i += 256)
        if (sacc[i]) atomicAdd(&accLab[i], sacc[i]);
}

// Pass 5: closed-form LOO combine in double (totals from segment sums)
__global__ __launch_bounds__(256) void k_final(const unsigned long long* __restrict__ segG,
                                               const int* __restrict__ cumN,
                                               const double* __restrict__ cumT,
                                               const double* __restrict__ cumQ,
                                               const unsigned long long* __restrict__ accLab,
                                               float* __restrict__ out) {
    __shared__ double red[256];
    const int t = threadIdx.x;
    double local = 0.0;
    for (int k = t; k < NCLS * NBINS; k += 256) {
        int c = k / NBINS, b = k - c * NBINS;
        double n, T, Q;
        if (b < NBINS - 1) {
            n = (double)(cumN[k + 1] - cumN[k]);
            T = cumT[k + 1] - cumT[k];
            Q = cumQ[k + 1] - cumQ[k];
        } else {
            unsigned long long uT = 0ull, uQ = 0ull;
            for (int j = 0; j < 16; ++j) {
                uT += segG[c * 32 + 2 * j];
                uQ += segG[c * 32 + 2 * j + 1];
            }
            n = (double)(NROWS - cumN[k]);
            T = (double)uT * FPI - cumT[k];
            Q = (double)uQ * FPI - cumQ[k];
        }
        double S = (double)accLab[k * 2 + 0];
        double T1 = (double)accLab[k * 2 + 1] * FPI;
        if (n > 1.5) {
            double inv = 1.0 / (n - 1.0);
            double a0 = S * inv, a1 = (S - 1.0) * inv;
            local += Q - 2.0 * a0 * T + 2.0 * T1 * inv + (n - S) * a0 * a0 + S * a1 * a1;
        }
    }
    red[t] = local;
    __syncthreads();
    for (int s = 128; s; s >>= 1) {
        if (t < s) red[t] += red[t + s];
        __syncthreads();
    }
    if (t == 0) out[0] = (float)(red[0] / ((double)NROWS * (double)NCLS));
}

extern "C" void kernel_launch(void* const* d_in, const int* in_sizes, int n_in,
                              void* d_out, int out_size, void* d_ws, size_t ws_size,
                              hipStream_t stream) {
    const float* logits = (const float*)d_in[0];
    const int* labels = (const int*)d_in[1];
    float* out = (float*)d_out;
    char* ws = (char*)d_ws;
    size_t off = 0;
    auto alloc = [&](size_t bytes) -> void* {
        off = (off + 255) & ~(size_t)255;
        void* p = ws + off;
        off += bytes;
        return p;
    };
    float* probsT = (float*)alloc((size_t)NCLS * NROWS * 4);               // 200 MB
    float* labConf = (float*)alloc((size_t)NROWS * 4);                     // 2 MB
    // --- zeroed region (contiguous, single small memset ~3.7 MB) ---
    char* zbase = ws + ((off + 255) & ~(size_t)255);
    unsigned*           histG  = (unsigned*)alloc((size_t)NCLS * 4096 * 4);        // 1.6 MB
    unsigned*           hnG    = (unsigned*)alloc((size_t)NCLS * HSZ * 4);         // 384 KB
    unsigned long long* hTG    = (unsigned long long*)alloc((size_t)NCLS * HSZ * 8); // 768 KB
    unsigned long long* hQG    = (unsigned long long*)alloc((size_t)NCLS * HSZ * 8); // 768 KB
    unsigned long long* segG   = (unsigned long long*)alloc((size_t)NCLS * 32 * 8);
    unsigned long long* accLab = (unsigned long long*)alloc((size_t)NCLS * NBINS * 2 * 8);
    size_t zlen = (size_t)((ws + off) - zbase);
    // --- written-before-read region ---
    int*    tgt     = (int*)alloc((size_t)NCLS * NBINS * 4);
    int*    below   = (int*)alloc((size_t)NCLS * NBINS * 4);
    int*    owner   = (int*)alloc((size_t)NCLS * NBINS * 4);
    float*  bounds  = (float*)alloc((size_t)NCLS * NBINS * 4);
    int*    cumN    = (int*)alloc((size_t)NCLS * NBINS * 4);
    double* cumT    = (double*)alloc((size_t)NCLS * NBINS * 8);
    double* cumQ    = (double*)alloc((size_t)NCLS * NBINS * 8);
    if (off > ws_size) {
        hipMemsetAsync(d_out, 0xFF, 4, stream);   // NaN sentinel
        return;
    }
    hipMemsetAsync(zbase, 0, zlen, stream);

    k_softmax_t<<<(NROWS + 63) / 64, 256, 0, stream>>>((const float4*)logits, labels,
                                                       probsT, labConf);
    k_hist1<<<dim3(B1, NCLS), 256, 0, stream>>>((const float4*)probsT, histG);
    k_sel1<<<NCLS, 256, 0, stream>>>(histG, tgt, below, owner);
    k_scan2<<<dim3(B2, NCLS), 256, 0, stream>>>((const float4*)probsT, tgt,
                                                hnG, hTG, hQG, segG);
    k_sel2<<<dim3(NBINS, NCLS), 64, 0, stream>>>(hnG, hTG, hQG, tgt, below, owner,
                                                 segG, bounds, cumN, cumT, cumQ);
    k_label<<<128, 256, 0, stream>>>(labConf, labels, bounds, accLab);
    k_final<<<1, 256, 0, stream>>>(segG, cumN, cumT, cumQ, accLab, out);
}